// Round 1
// baseline (291.704 us; speedup 1.0000x reference)
//
#include <hip/hip_runtime.h>
#include <hip/hip_bf16.h>

#define SEQ 2048
#define DM  1024
#define NH  4
#define HD  256

typedef __attribute__((ext_vector_type(4))) float f32x4;
typedef __attribute__((ext_vector_type(8))) short bf16x8;

__device__ __forceinline__ void gload16(const void* g, void* l) {
  __builtin_amdgcn_global_load_lds(
      (__attribute__((address_space(1))) void*)(unsigned long long)(g),
      (__attribute__((address_space(3))) void*)(l), 16, 0, 0);
}

__device__ __forceinline__ bf16x8 ldg8(const __hip_bfloat16* p) {
  return *reinterpret_cast<const bf16x8*>(p);
}

// ---------------- fp32 -> bf16 ----------------
__global__ __launch_bounds__(256) void cvt_f32_bf16(const float* __restrict__ in,
                                                    __hip_bfloat16* __restrict__ out, int n4) {
  int i = blockIdx.x * 256 + threadIdx.x;
  if (i >= n4) return;
  float4 v = reinterpret_cast<const float4*>(in)[i];
  __hip_bfloat162* o2 = reinterpret_cast<__hip_bfloat162*>(out);
  o2[i * 2 + 0] = __float22bfloat162_rn(make_float2(v.x, v.y));
  o2[i * 2 + 1] = __float22bfloat162_rn(make_float2(v.z, v.w));
}

// ---------------- GEMM: C[m,n] = sum_k A[m,k]*B[n,k] (+bias, +resid) ----------------
// 128x128 tile, BK=32, 4 waves, 4x4 16x16x32 frags/wave, global_load_lds staging (m97 structure)
template <int EPI>
__global__ __launch_bounds__(256, 2) void gemm_bt(
    const __hip_bfloat16* __restrict__ A, const __hip_bfloat16* __restrict__ Bw,
    const float* __restrict__ bias, const float* __restrict__ resid,
    __hip_bfloat16* __restrict__ Cb, float* __restrict__ Cf, int M, int N, int K) {
  __shared__ __hip_bfloat16 ldsA[128 * 32];
  __shared__ __hip_bfloat16 ldsB[128 * 32];
  const int t = threadIdx.x;
  const int w = t >> 6, l = t & 63;
  const int lg = l >> 4, li = l & 15;
  const int m0 = blockIdx.y * 128, n0 = blockIdx.x * 128;
  const int wm = (w >> 1) * 64, wn = (w & 1) * 64;
  const int c1 = t + 256;
  const __hip_bfloat16* gA0 = A + (size_t)(m0 + (t >> 2)) * K + (t & 3) * 8;
  const __hip_bfloat16* gA1 = A + (size_t)(m0 + (c1 >> 2)) * K + (c1 & 3) * 8;
  const __hip_bfloat16* gB0 = Bw + (size_t)(n0 + (t >> 2)) * K + (t & 3) * 8;
  const __hip_bfloat16* gB1 = Bw + (size_t)(n0 + (c1 >> 2)) * K + (c1 & 3) * 8;
  __hip_bfloat16* lA0 = ldsA + t * 8;
  __hip_bfloat16* lA1 = ldsA + c1 * 8;
  __hip_bfloat16* lB0 = ldsB + t * 8;
  __hip_bfloat16* lB1 = ldsB + c1 * 8;
  f32x4 acc[4][4] = {};
  for (int k0 = 0; k0 < K; k0 += 32) {
    gload16(gA0 + k0, lA0);
    gload16(gA1 + k0, lA1);
    gload16(gB0 + k0, lB0);
    gload16(gB1 + k0, lB1);
    __syncthreads();
    bf16x8 af[4], bfr[4];
#pragma unroll
    for (int i = 0; i < 4; i++) af[i] = ldg8(&ldsA[(wm + i * 16 + li) * 32 + lg * 8]);
#pragma unroll
    for (int i = 0; i < 4; i++) bfr[i] = ldg8(&ldsB[(wn + i * 16 + li) * 32 + lg * 8]);
#pragma unroll
    for (int mi = 0; mi < 4; mi++)
#pragma unroll
      for (int ni = 0; ni < 4; ni++)
        acc[mi][ni] = __builtin_amdgcn_mfma_f32_16x16x32_bf16(af[mi], bfr[ni], acc[mi][ni], 0, 0, 0);
    __syncthreads();
  }
#pragma unroll
  for (int ni = 0; ni < 4; ni++) {
    const int col = n0 + wn + ni * 16 + li;
    const float bv = bias[col];
#pragma unroll
    for (int mi = 0; mi < 4; mi++) {
      const int rowb = m0 + wm + mi * 16 + lg * 4;
#pragma unroll
      for (int r = 0; r < 4; r++) {
        const size_t idx = (size_t)(rowb + r) * N + col;
        float v = acc[mi][ni][r] + bv;
        if (EPI) {
          Cf[idx] = v + resid[idx];
        } else {
          Cb[idx] = __float2bfloat16(v);
        }
      }
    }
  }
}

// ---------------- V transpose: vt[bh][d][s] <- qkv[.., 2048 + h*256 + d] ----------------
__global__ __launch_bounds__(256) void transpose_v(const short* __restrict__ qkv,
                                                   short* __restrict__ vt) {
  __shared__ short tile[32][36];
  const int t = threadIdx.x;
  const int bh = blockIdx.z, b = bh >> 2, h = bh & 3;
  const int s0 = blockIdx.x * 32, d0 = blockIdx.y * 32;
  const int sr = t >> 3, c4 = (t & 7) * 4;
  const short* src = qkv + (size_t)(b * SEQ + s0 + sr) * 3072 + 2048 + h * HD + d0 + c4;
  short4 vv = *reinterpret_cast<const short4*>(src);
  tile[sr][c4 + 0] = vv.x;
  tile[sr][c4 + 1] = vv.y;
  tile[sr][c4 + 2] = vv.z;
  tile[sr][c4 + 3] = vv.w;
  __syncthreads();
  short* dst = vt + (size_t)(bh * HD + d0 + sr) * SEQ + s0 + c4;
  short4 ov;
  ov.x = tile[c4 + 0][sr];
  ov.y = tile[c4 + 1][sr];
  ov.z = tile[c4 + 2][sr];
  ov.w = tile[c4 + 3][sr];
  *reinterpret_cast<short4*>(dst) = ov;
}

// ---------------- flash attention v3: double-buffered pipelined K/V tiles ----------------
// 1-D grid of 512 blocks; bid&7 selects XCD (measured round-robin) -> each XCD owns exactly
// 2 bh => K+V working set 4 MB = one L2 (T1 analog for L2 locality).
// KVBLK=32, K/V double-buffered in LDS: stage tile t+1 BEFORE computing tile t; single
// __syncthreads per iter (its implicit vmcnt(0) lands after ~900 cyc of compute -> ~free).
// Swizzles (rule #21: linear LDS dest + inverse-swizzled global src + swizzled read):
//   K: 32 rows x 512 B, stored 16B-chunk c holds data chunk c ^ (row&7)   -> reads 2-way aliased
//   V: 256 rows x 64 B, stored chunk c holds data chunk c ^ ((row>>2)&3)  -> reads 2-way aliased
//   P: 16 rows x 64 B,  stored chunk c holds data chunk c ^ ((row>>1)&3)  -> reads 2-way aliased
// Defer-max (T13, THR=8): skip O-rescale while per-tile max growth <= 8.
__global__ __launch_bounds__(256, 2) void flash_attn(const __hip_bfloat16* __restrict__ qkv,
                                                     const __hip_bfloat16* __restrict__ vt,
                                                     __hip_bfloat16* __restrict__ attno) {
  __shared__ __hip_bfloat16 ldsK[2][32 * 256];  // 2 x 16 KB
  __shared__ __hip_bfloat16 ldsV[2][256 * 32];  // 2 x 16 KB
  __shared__ __hip_bfloat16 ldsP[4][16 * 32];   // 4 KB   (total 68 KB -> 2 blocks/CU)
  const int tid = threadIdx.x, w = tid >> 6, l = tid & 63;
  const int lg = l >> 4, li = l & 15;
  const int bid = blockIdx.x;
  const int qt = bid >> 4;
  const int bh = (bid & 7) * 2 + ((bid >> 3) & 1);  // bijective; XCD = bid&7 -> 2 bh per XCD
  const int b = bh >> 2, h = bh & 3;
  const int q0 = qt * 64 + w * 16;
  // Q rows for this wave, A-fragment layout: row=l&15, k=(l>>4)*8 contiguous
  const __hip_bfloat16* Qp = qkv + (size_t)(b * SEQ + q0 + li) * 3072 + h * HD + lg * 8;
  bf16x8 aq[8];
#pragma unroll
  for (int kk = 0; kk < 8; kk++) aq[kk] = ldg8(Qp + kk * 32);
  // staging source bases (pre-swizzled global addresses)
  // K round i (i<4): lds row = i*8 + (tid>>5), stored chunk = tid&31, data chunk = (tid&31)^(row&7)
  const int kcd = (tid & 31) ^ ((tid >> 5) & 7);
  const __hip_bfloat16* Kg = qkv + (size_t)(b * SEQ + (tid >> 5)) * 3072 + 1024 + h * HD + kcd * 8;
  // V round i (i<4): lds row d = i*64 + (tid>>2), stored chunk = tid&3, data chunk = (tid&3)^((d>>2)&3)
  const int vcd = (tid & 3) ^ ((tid >> 4) & 3);
  const __hip_bfloat16* Vg = vt + (size_t)bh * HD * SEQ + (size_t)(tid >> 2) * SEQ + vcd * 8;
  __hip_bfloat16* Pw = &ldsP[w][0];
  f32x4 oacc[16] = {};
  float mst[4], lst[4];
#pragma unroll
  for (int r = 0; r < 4; r++) { mst[r] = -1e30f; lst[r] = 0.f; }
  // prologue: stage tile 0 into buffer 0 (the only exposed staging latency)
#pragma unroll
  for (int i = 0; i < 4; i++) gload16(Kg + (size_t)(i * 8) * 3072, &ldsK[0][i * 2048 + tid * 8]);
#pragma unroll
  for (int i = 0; i < 4; i++) gload16(Vg + (size_t)(i * 64) * SEQ, &ldsV[0][i * 2048 + tid * 8]);
  __syncthreads();
#pragma unroll 2
  for (int t = 0; t < SEQ / 32; ++t) {
    const int cur = t & 1;
    // ---- issue next tile's loads first: latency hides under this tile's compute ----
    if (t + 1 < SEQ / 32) {
      const int nk = (t + 1) * 32;
#pragma unroll
      for (int i = 0; i < 4; i++)
        gload16(Kg + (size_t)(nk + i * 8) * 3072, &ldsK[cur ^ 1][i * 2048 + tid * 8]);
#pragma unroll
      for (int i = 0; i < 4; i++)
        gload16(Vg + (size_t)(i * 64) * SEQ + nk, &ldsV[cur ^ 1][i * 2048 + tid * 8]);
    }
    const __hip_bfloat16* Kb = &ldsK[cur][0];
    const __hip_bfloat16* Vb = &ldsV[cur][0];
    // ---- QK^T from LDS (16 MFMA) ----
    f32x4 sacc[2] = {};
#pragma unroll
    for (int kk = 0; kk < 8; kk++) {
#pragma unroll
      for (int nf = 0; nf < 2; nf++) {
        const int r = nf * 16 + li;
        bf16x8 bk = ldg8(&Kb[r * 256 + (((kk * 4 + lg) ^ (li & 7)) << 3)]);
        sacc[nf] = __builtin_amdgcn_mfma_f32_16x16x32_bf16(aq[kk], bk, sacc[nf], 0, 0, 0);
      }
    }
    // ---- online softmax (wave-parallel 16-lane groups, defer-max THR=8) ----
#pragma unroll
    for (int r = 0; r < 4; r++) {
      const float s0 = sacc[0][r] * 0.0625f;  // hd^-0.5
      const float s1 = sacc[1][r] * 0.0625f;
      float rmax = fmaxf(s0, s1);
#pragma unroll
      for (int off = 1; off < 16; off <<= 1) rmax = fmaxf(rmax, __shfl_xor(rmax, off));
      if (rmax > mst[r] + 8.f) {  // group-uniform: rescale only on real max growth
        const float alpha = __expf(mst[r] - rmax);
        mst[r] = rmax;
        lst[r] *= alpha;
#pragma unroll
        for (int df = 0; df < 16; df++) oacc[df][r] *= alpha;
      }
      const float p0 = __expf(s0 - mst[r]);  // bounded by e^8
      const float p1 = __expf(s1 - mst[r]);
      float ps = p0 + p1;
#pragma unroll
      for (int off = 1; off < 16; off <<= 1) ps += __shfl_xor(ps, off);
      lst[r] += ps;
      const int q = lg * 4 + r;
      const int swzp = (q >> 1) & 3;
      Pw[q * 32 + (((0 + (li >> 3)) ^ swzp) << 3) + (li & 7)] = __float2bfloat16(p0);
      Pw[q * 32 + (((2 + (li >> 3)) ^ swzp) << 3) + (li & 7)] = __float2bfloat16(p1);
    }
    asm volatile("" ::: "memory");
    // ---- PV from LDS (wave-private P; DS in-order within wave) ----
    bf16x8 pa = ldg8(&Pw[li * 32 + ((lg ^ ((li >> 1) & 3)) << 3)]);
#pragma unroll
    for (int df = 0; df < 16; df++) {
      const int d = df * 16 + li;
      bf16x8 bv = ldg8(&Vb[d * 32 + ((lg ^ (li >> 2)) << 3)]);
      oacc[df] = __builtin_amdgcn_mfma_f32_16x16x32_bf16(pa, bv, oacc[df], 0, 0, 0);
    }
    // one barrier per iter: drains next tile's loads (in flight during compute) AND
    // guards buffer reuse for the stage issued at t+1
    __syncthreads();
  }
  const float inv0 = 1.f / lst[0], inv1 = 1.f / lst[1];
  const float inv2 = 1.f / lst[2], inv3 = 1.f / lst[3];
  const float inv[4] = {inv0, inv1, inv2, inv3};
  const size_t orow = (size_t)(b * SEQ + qt * 64 + w * 16 + lg * 4);
#pragma unroll
  for (int df = 0; df < 16; df++)
#pragma unroll
    for (int r = 0; r < 4; r++) {
      float v = oacc[df][r] * inv[r];
      attno[(orow + r) * DM + h * HD + df * 16 + li] = __float2bfloat16(v);
    }
}

// ---------------- LayerNorm: 1 wave per 1024-row ----------------
__global__ __launch_bounds__(256) void layernorm_k(const float* __restrict__ y,
                                                   const float* __restrict__ gamma,
                                                   const float* __restrict__ beta,
                                                   float* __restrict__ out) {
  const int w = threadIdx.x >> 6, l = threadIdx.x & 63;
  const size_t row = (size_t)blockIdx.x * 4 + w;
  const float4* yp = reinterpret_cast<const float4*>(y + row * DM);
  float4 v[4];
  float s = 0.f, s2 = 0.f;
#pragma unroll
  for (int i = 0; i < 4; i++) {
    v[i] = yp[i * 64 + l];
    s += v[i].x + v[i].y + v[i].z + v[i].w;
    s2 += v[i].x * v[i].x + v[i].y * v[i].y + v[i].z * v[i].z + v[i].w * v[i].w;
  }
#pragma unroll
  for (int off = 1; off < 64; off <<= 1) {
    s += __shfl_xor(s, off);
    s2 += __shfl_xor(s2, off);
  }
  const float mu = s * (1.f / 1024.f);
  const float rs = rsqrtf(s2 * (1.f / 1024.f) - mu * mu + 1e-5f);
  const float4* gp = reinterpret_cast<const float4*>(gamma);
  const float4* bp = reinterpret_cast<const float4*>(beta);
  float4* op = reinterpret_cast<float4*>(out + row * DM);
#pragma unroll
  for (int i = 0; i < 4; i++) {
    float4 g = gp[i * 64 + l], bb = bp[i * 64 + l];
    float4 o;
    o.x = (v[i].x - mu) * rs * g.x + bb.x;
    o.y = (v[i].y - mu) * rs * g.y + bb.y;
    o.z = (v[i].z - mu) * rs * g.z + bb.z;
    o.w = (v[i].w - mu) * rs * g.w + bb.w;
    op[i * 64 + l] = o;
  }
}

extern "C" void kernel_launch(void* const* d_in, const int* in_sizes, int n_in,
                              void* d_out, int out_size, void* d_ws, size_t ws_size,
                              hipStream_t stream) {
  const float* x     = (const float*)d_in[0];
  const float* qkv_w = (const float*)d_in[1];
  const float* qkv_b = (const float*)d_in[2];
  const float* wo_w  = (const float*)d_in[3];
  const float* wo_b  = (const float*)d_in[4];
  const float* gamma = (const float*)d_in[5];
  const float* beta  = (const float*)d_in[6];
  float* out = (float*)d_out;
  char* ws = (char*)d_ws;
  __hip_bfloat16* xbf   = (__hip_bfloat16*)(ws);
  __hip_bfloat16* qkvwb = (__hip_bfloat16*)(ws + 16777216);
  __hip_bfloat16* wowb  = (__hip_bfloat16*)(ws + 23068672);
  __hip_bfloat16* qkv   = (__hip_bfloat16*)(ws + 25165824);
  float*          yb    = (float*)(ws + 25165824);
  __hip_bfloat16* vt    = (__hip_bfloat16*)(ws + 75497472);
  __hip_bfloat16* attno = xbf;

  cvt_f32_bf16<<<8192, 256, 0, stream>>>(x, xbf, 2097152);
  cvt_f32_bf16<<<3072, 256, 0, stream>>>(qkv_w, qkvwb, 786432);
  cvt_f32_bf16<<<1024, 256, 0, stream>>>(wo_w, wowb, 262144);
  gemm_bt<0><<<dim3(24, 64), 256, 0, stream>>>(xbf, qkvwb, qkv_b, nullptr, qkv, nullptr,
                                               8192, 3072, 1024);
  transpose_v<<<dim3(64, 8, 16), 256, 0, stream>>>((const short*)qkv, (short*)vt);
  flash_attn<<<512, 256, 0, stream>>>(qkv, vt, attno);
  gemm_bt<1><<<dim3(8, 64), 256, 0, stream>>>(attno, wowb, wo_b, x, nullptr, yb,
                                              8192, 1024, 1024);
  layernorm_k<<<2048, 256, 0, stream>>>(yb, gamma, beta, out);
}